// Round 9
// baseline (6962.273 us; speedup 1.0000x reference)
//
#include <hip/hip_runtime.h>
#include <math.h>

// Problem constants
#define BATCH 32
#define SEQ 256
#define EMBD 256
#define HDIM 256          // per-direction hidden
#define G4H 1024          // 4*H gates per direction
#define TAGS 12
#define START_IDX 10
#define STOP_IDX 11
#define NEGV -10000.0f

// Recurrence weight split (per gate row, K = 256):
//   k in [0,48)    : VGPR-resident (12 float4, asm-anchored; fits 128-reg budget)
//   k in [48,84)   : LDS-resident  (9 float4 groups, 147 KB staged once)
//   k in [84,256)  : streamed from L2 each step (43 float4 groups, depth-4 prefetch)
#define KRES 48
#define KLDS_G 9
#define KSTR_G 43

// ---------------- Workspace layout (floats) ----------------
// xg     : [2][8192][1024]            = 16,777,216
// x      : [8192][256]                =  2,097,152
// wpack  : [2][43][1024] float4       =    352,256 floats
// h_all  : [32][256][512]             =  4,194,304
// feats  : [32][256][12]              =     98,304
#define WS_XG    0
#define WS_X     16777216
#define WS_WPACK 18874368
#define WS_HALL  19234816
#define WS_FEATS 23429120

// broadcast h[k] from lane-distributed VGPR (compile-time lane index)
__device__ __forceinline__ float bcast(float v, int l) {
    return __int_as_float(__builtin_amdgcn_readlane(__float_as_int(v), l));
}

// ---------------- Kernel 1: gather embeddings ----------------
__global__ void gather_x(const int* __restrict__ sent, const float* __restrict__ emb,
                         float* __restrict__ x) {
    int m = blockIdx.x;            // 8192 positions (b*256+s)
    int lane = threadIdx.x;        // 64
    long long row = sent[m];
    float4 v = *(const float4*)(emb + row * EMBD + lane * 4);
    *(float4*)(x + (size_t)m * EMBD + lane * 4) = v;
}

// ---------------- Kernel 2: pack streamed tail of whh, coalesced layout ----
// wpack[dir][k4][g] = whh_dir[g][84 + 4*k4 .. +3]
__global__ void pack_whh(const float* __restrict__ whh_f, const float* __restrict__ whh_b,
                         float4* __restrict__ pack) {
    int idx = blockIdx.x * 256 + threadIdx.x;      // 2*43*1024 = 88064
    if (idx >= 2 * KSTR_G * G4H) return;
    int g = idx & 1023;
    int r = idx >> 10;
    int k4 = r % KSTR_G;
    int dir = r / KSTR_G;
    const float* w = dir ? whh_b : whh_f;
    pack[idx] = *(const float4*)(w + (size_t)g * HDIM + KRES + 4 * KLDS_G + k4 * 4);
}

// ---------------- Kernel 3: xg GEMM  C[8192][2048] ----------------
__launch_bounds__(256)
__global__ void gemm_xg(const float* __restrict__ x,
                        const float* __restrict__ wih_f, const float* __restrict__ wih_b,
                        const float* __restrict__ bih_f, const float* __restrict__ bhh_f,
                        const float* __restrict__ bih_b, const float* __restrict__ bhh_b,
                        float* __restrict__ xg) {
    __shared__ __align__(16) float as[8][128];
    __shared__ __align__(16) float bs[8][128];
    int m0 = blockIdx.x * 128;     // 64 tiles
    int n0 = blockIdx.y * 128;     // 16 tiles
    int tid = threadIdx.x;
    int tx = tid & 15, ty = tid >> 4;
    int lr = tid >> 1;             // 0..127 tile row
    int lh = (tid & 1) * 4;        // k offset 0 or 4

    const float* arow = x + (size_t)(m0 + lr) * EMBD;
    const float* brow;
    {
        int n = n0 + lr;
        const float* w = (n < G4H) ? wih_f : wih_b;
        brow = w + (size_t)(n & 1023) * EMBD;
    }

    float acc[8][8];
    #pragma unroll
    for (int i = 0; i < 8; i++)
        #pragma unroll
        for (int j = 0; j < 8; j++) acc[i][j] = 0.f;

    for (int k0 = 0; k0 < EMBD; k0 += 8) {
        float4 av = *(const float4*)(arow + k0 + lh);
        float4 bv = *(const float4*)(brow + k0 + lh);
        __syncthreads();
        as[lh + 0][lr] = av.x; as[lh + 1][lr] = av.y; as[lh + 2][lr] = av.z; as[lh + 3][lr] = av.w;
        bs[lh + 0][lr] = bv.x; bs[lh + 1][lr] = bv.y; bs[lh + 2][lr] = bv.z; bs[lh + 3][lr] = bv.w;
        __syncthreads();
        #pragma unroll
        for (int kk = 0; kk < 8; kk++) {
            float4 a0 = *(const float4*)&as[kk][ty * 8];
            float4 a1 = *(const float4*)&as[kk][ty * 8 + 4];
            float4 b0 = *(const float4*)&bs[kk][tx * 8];
            float4 b1 = *(const float4*)&bs[kk][tx * 8 + 4];
            float a[8] = {a0.x, a0.y, a0.z, a0.w, a1.x, a1.y, a1.z, a1.w};
            float b[8] = {b0.x, b0.y, b0.z, b0.w, b1.x, b1.y, b1.z, b1.w};
            #pragma unroll
            for (int i = 0; i < 8; i++)
                #pragma unroll
                for (int j = 0; j < 8; j++) acc[i][j] += a[i] * b[j];
        }
    }

    // epilogue: + bih + bhh (reference order), store to xg[dir] base
    int n = n0 + tx * 8;                 // tile stays within one dir (1024 % 128 == 0)
    int dir = n >> 10, g0 = n & 1023;
    const float* bih = dir ? bih_b : bih_f;
    const float* bhh = dir ? bhh_b : bhh_f;
    float bi[8], bh[8];
    #pragma unroll
    for (int j = 0; j < 8; j++) { bi[j] = bih[g0 + j]; bh[j] = bhh[g0 + j]; }
    float* ob = xg + (size_t)dir * 8192 * G4H;
    #pragma unroll
    for (int i = 0; i < 8; i++) {
        int m = m0 + ty * 8 + i;
        float v[8];
        #pragma unroll
        for (int j = 0; j < 8; j++) v[j] = (acc[i][j] + bi[j]) + bh[j];
        *(float4*)(ob + (size_t)m * G4H + g0)     = make_float4(v[0], v[1], v[2], v[3]);
        *(float4*)(ob + (size_t)m * G4H + g0 + 4) = make_float4(v[4], v[5], v[6], v[7]);
    }
}

// ---------------- Kernel 4: LSTM recurrence ----------------
// One WG per (batch, direction). Thread g owns gate row g (K=256 dot with h).
// h broadcast via v_readlane from 4 lane-distributed VGPRs (no per-k LDS reads).
// amdgpu_waves_per_eu(4,4): pin occupancy target to 4 waves/EU (= 1 WG/CU, which
// the 152 KB LDS forces anyway) -> register budget 128, so the ~88-reg live set
// does not spill. __launch_bounds__(1024,4) alone is only a FLOOR (min waves/EU)
// and the allocator still targeted 8 waves/EU -> 64-reg budget -> scratch spill
// (measured R4/R8: VGPR=64, FETCH 6.4 GB, 6.6 ms).
#define DOT4(W, K)                                              \
    a0 += (W).x * bcast(hv[((K) + 0) >> 6], ((K) + 0) & 63);    \
    a1 += (W).y * bcast(hv[((K) + 1) >> 6], ((K) + 1) & 63);    \
    a2 += (W).z * bcast(hv[((K) + 2) >> 6], ((K) + 2) & 63);    \
    a3 += (W).w * bcast(hv[((K) + 3) >> 6], ((K) + 3) & 63);

__global__ void __launch_bounds__(1024)
__attribute__((amdgpu_waves_per_eu(4, 4)))
lstm_rec(const float* __restrict__ xg,
         const float* __restrict__ whh_f, const float* __restrict__ whh_b,
         const float4* __restrict__ wpack,
         float* __restrict__ h_all) {
    int blk = blockIdx.x;          // 64
    int dir = blk & 1, b = blk >> 1;
    int g = threadIdx.x;           // 0..1023
    int lane = g & 63;
    const float* whh = dir ? whh_b : whh_f;
    const float4* wp = wpack + (size_t)dir * KSTR_G * G4H + g;   // thread's stream base
    const float* xgb = xg + (size_t)dir * 8192 * G4H + (size_t)b * SEQ * G4H + g;

    __shared__ __align__(16) float4 wlds[KLDS_G * G4H];   // 147,456 B
    __shared__ float h_lds[HDIM];                         //   1,024 B
    __shared__ float gates[G4H];                          //   4,096 B

    // stage LDS weights (k = 48..84), one-time
    #pragma unroll
    for (int j = 0; j < KLDS_G; j++)
        wlds[j * G4H + g] = *(const float4*)(whh + (size_t)g * HDIM + KRES + j * 4);

    // VGPR-resident weights k = 0..47; asm anchor pins the loads here so the
    // compiler cannot sink them into the t-loop
    float4 wr[KRES / 4];
    #pragma unroll
    for (int i = 0; i < KRES / 4; i++) {
        wr[i] = *(const float4*)(whh + (size_t)g * HDIM + i * 4);
        asm volatile("" : "+v"(wr[i].x), "+v"(wr[i].y), "+v"(wr[i].z), "+v"(wr[i].w));
    }

    float c = 0.f;
    if (g < HDIM) h_lds[g] = 0.f;
    __syncthreads();

    for (int t = 0; t < SEQ; t++) {
        int s = dir ? (SEQ - 1 - t) : t;

        // issue long-latency loads first: xg value + prime the stream ring
        float xval = xgb[(size_t)s * G4H];
        float4 sb[4];
        #pragma unroll
        for (int p = 0; p < 4; p++) sb[p] = wp[(size_t)p * G4H];

        // h for this step: 4 lane-distributed LDS reads per thread
        float hv[4];
        #pragma unroll
        for (int j = 0; j < 4; j++) hv[j] = h_lds[j * 64 + lane];

        float a0 = xval, a1 = 0.f, a2 = 0.f, a3 = 0.f;

        // resident portion k = 0..47 (pure register ops)
        #pragma unroll
        for (int i = 0; i < KRES / 4; i++) {
            float4 w = wr[i];
            DOT4(w, i * 4)
        }
        // LDS portion k = 48..84
        #pragma unroll
        for (int j = 0; j < KLDS_G; j++) {
            float4 w = wlds[j * G4H + g];
            DOT4(w, KRES + j * 4)
        }
        // streamed portion k = 84..256, depth-4 prefetch ring (static indices)
        #pragma unroll
        for (int j = 0; j < KSTR_G; j++) {
            float4 w = sb[j & 3];
            if (j + 4 < KSTR_G) sb[j & 3] = wp[(size_t)(j + 4) * G4H];
            DOT4(w, KRES + 4 * KLDS_G + j * 4)
        }

        gates[g] = (a0 + a1) + (a2 + a3);
        __syncthreads();
        if (g < HDIM) {
            float gi = gates[g], gf = gates[HDIM + g], gg = gates[2 * HDIM + g], go = gates[3 * HDIM + g];
            float si = 1.f / (1.f + expf(-gi));
            float sf = 1.f / (1.f + expf(-gf));
            float so = 1.f / (1.f + expf(-go));
            c = sf * c + si * tanhf(gg);
            float h = so * tanhf(c);
            h_lds[g] = h;
            h_all[((size_t)b * SEQ + s) * 512 + dir * HDIM + g] = h;
        }
        __syncthreads();
    }
}

// ---------------- Kernel 5: output projection (feats) ----------------
__global__ void feats_kernel(const float* __restrict__ h_all, const float* __restrict__ w_out,
                             const float* __restrict__ b_out, float* __restrict__ feats) {
    int p = blockIdx.x;            // 8192
    int lane = threadIdx.x;        // 64
    const float* h = h_all + (size_t)p * 512;
    for (int f = 0; f < TAGS; f++) {
        float s = 0.f;
        const float* w = w_out + f * 512;
        #pragma unroll
        for (int k = 0; k < 512; k += 64) s += h[k + lane] * w[k + lane];
        #pragma unroll
        for (int off = 32; off; off >>= 1) s += __shfl_down(s, off);
        if (lane == 0) feats[(size_t)p * TAGS + f] = s + b_out[f];
    }
}

// ---------------- Kernel 6: Viterbi decode ----------------
__global__ void viterbi_kernel(const float* __restrict__ feats, const float* __restrict__ trans,
                               float* __restrict__ out) {
    int b = blockIdx.x;            // 32
    int t = threadIdx.x;           // 64
    __shared__ float fv[TAGS], fvn[TAGS], tr[TAGS * TAGS];
    __shared__ int bp[SEQ][TAGS];  // 12 KB

    for (int i = t; i < TAGS * TAGS; i += 64) tr[i] = trans[i];
    if (t < TAGS) fv[t] = (t == START_IDX) ? 0.f : NEGV;
    __syncthreads();

    const float* fb = feats + (size_t)b * SEQ * TAGS;
    for (int s = 0; s < SEQ; s++) {
        if (t < TAGS) {
            float best = fv[0] + tr[t * TAGS + 0];
            int bi = 0;
            #pragma unroll
            for (int prev = 1; prev < TAGS; prev++) {
                float v = fv[prev] + tr[t * TAGS + prev];
                if (v > best) { best = v; bi = prev; }   // first-index argmax
            }
            bp[s][t] = bi;
            fvn[t] = best + fb[s * TAGS + t];
        }
        __syncthreads();
        if (t < TAGS) fv[t] = fvn[t];
        __syncthreads();
    }

    if (t == 0) {
        float best = fv[0] + tr[STOP_IDX * TAGS + 0];
        int bi = 0;
        #pragma unroll
        for (int p = 1; p < TAGS; p++) {
            float v = fv[p] + tr[STOP_IDX * TAGS + p];
            if (v > best) { best = v; bi = p; }
        }
        out[b] = best;                                   // score
        float* path = out + BATCH + (size_t)b * SEQ;
        int tag = bi;
        path[SEQ - 1] = (float)tag;
        for (int s = SEQ - 1; s >= 1; s--) {
            tag = bp[s][tag];
            path[s - 1] = (float)tag;
        }
    }
}

// ---------------- Launch ----------------
extern "C" void kernel_launch(void* const* d_in, const int* in_sizes, int n_in,
                              void* d_out, int out_size, void* d_ws, size_t ws_size,
                              hipStream_t stream) {
    const int*   sent  = (const int*)d_in[0];
    const float* emb   = (const float*)d_in[1];
    const float* wih_f = (const float*)d_in[2];
    const float* whh_f = (const float*)d_in[3];
    const float* bih_f = (const float*)d_in[4];
    const float* bhh_f = (const float*)d_in[5];
    const float* wih_b = (const float*)d_in[6];
    const float* whh_b = (const float*)d_in[7];
    const float* bih_b = (const float*)d_in[8];
    const float* bhh_b = (const float*)d_in[9];
    const float* w_out = (const float*)d_in[10];
    const float* b_out = (const float*)d_in[11];
    const float* trans = (const float*)d_in[12];
    float* ws    = (float*)d_ws;
    float* xg    = ws + WS_XG;
    float* x     = ws + WS_X;
    float* wpack = ws + WS_WPACK;
    float* h_all = ws + WS_HALL;
    float* feats = ws + WS_FEATS;
    float* out   = (float*)d_out;

    gather_x<<<BATCH * SEQ, 64, 0, stream>>>(sent, emb, x);
    pack_whh<<<(2 * KSTR_G * G4H + 255) / 256, 256, 0, stream>>>(whh_f, whh_b, (float4*)wpack);
    gemm_xg<<<dim3(64, 16), 256, 0, stream>>>(x, wih_f, wih_b, bih_f, bhh_f, bih_b, bhh_b, xg);
    lstm_rec<<<64, 1024, 0, stream>>>(xg, whh_f, whh_b, (const float4*)wpack, h_all);
    feats_kernel<<<BATCH * SEQ, 64, 0, stream>>>(h_all, w_out, b_out, feats);
    viterbi_kernel<<<BATCH, 64, 0, stream>>>(feats, trans, out);
}

// Round 10
// 1620.004 us; speedup vs baseline: 4.2977x; 4.2977x over previous
//
#include <hip/hip_runtime.h>
#include <math.h>

// Problem constants
#define BATCH 32
#define SEQ 256
#define EMBD 256
#define HDIM 256          // per-direction hidden
#define G4H 1024          // 4*H gates per direction
#define TAGS 12
#define START_IDX 10
#define STOP_IDX 11
#define NEGV -10000.0f

// lstm_rec: 2 WGs per (batch,dir) chain, split by hidden unit (128 units each).
// Per WG: 512 gate rows, K=256 dot. Weight tiers per row:
//   k in [0,16)   : VGPR (4 float4; live set ~55 regs fits the 64-reg budget)
//   k in [16,88)  : LDS (18 float4 groups, 147,456 B staged once)
//   k in [88,256) : streamed from L2 (42 float4 groups, depth-4 ring)
// Per-CU weight stream = 344 KB/step vs 1 MB/step in the 1-WG layout ->
// attacks the measured per-CU L2-BW bound (15.3k cyc/step @ VALUBusy 12.9%).
#define KRES 16
#define KLDS_G 18
#define KSTR_G 42

// ---------------- Workspace layout (floats) ----------------
// xg     : [2][8192][1024]            = 16,777,216
// x      : [8192][256]                =  2,097,152   (dead after gemm_xg;
//           hx (64*512) + flags (128) live at its start during lstm_rec)
// wpack  : [2][2][42][512] float4     =    344,064 floats
// h_all  : [32][256][512]             =  4,194,304
// feats  : [32][256][12]              =     98,304
#define WS_XG    0
#define WS_X     16777216
#define WS_WPACK 18874368
#define WS_HALL  19234816
#define WS_FEATS 23429120

// broadcast h[k] from lane-distributed VGPR (compile-time lane index)
__device__ __forceinline__ float bcast(float v, int l) {
    return __int_as_float(__builtin_amdgcn_readlane(__float_as_int(v), l));
}

// ---------------- Kernel 1: gather embeddings ----------------
__global__ void gather_x(const int* __restrict__ sent, const float* __restrict__ emb,
                         float* __restrict__ x) {
    int m = blockIdx.x;            // 8192 positions (b*256+s)
    int lane = threadIdx.x;        // 64
    long long row = sent[m];
    float4 v = *(const float4*)(emb + row * EMBD + lane * 4);
    *(float4*)(x + (size_t)m * EMBD + lane * 4) = v;
}

// ---------------- Kernel 2: pack streamed tail of whh ----------------
// wpack[((dir*2+half)*42+j)*512+g] = whh_dir[R(g,half)][88+4j .. +3]
// R(g,half) = (g>>7)*256 + half*128 + (g&127)
__global__ void pack_whh(const float* __restrict__ whh_f, const float* __restrict__ whh_b,
                         float4* __restrict__ pack) {
    int idx = blockIdx.x * 256 + threadIdx.x;      // 2*2*42*512 = 86016
    if (idx >= 2 * 2 * KSTR_G * 512) return;
    int g = idx & 511;
    int r = idx >> 9;
    int j = r % KSTR_G; r /= KSTR_G;
    int half = r & 1, dir = r >> 1;
    int R = (g >> 7) * 256 + half * 128 + (g & 127);
    const float* w = dir ? whh_b : whh_f;
    pack[idx] = *(const float4*)(w + (size_t)R * HDIM + KRES + 4 * KLDS_G + 4 * j);
}

// ---------------- Kernel 3: xg GEMM  C[8192][2048] ----------------
__launch_bounds__(256)
__global__ void gemm_xg(const float* __restrict__ x,
                        const float* __restrict__ wih_f, const float* __restrict__ wih_b,
                        const float* __restrict__ bih_f, const float* __restrict__ bhh_f,
                        const float* __restrict__ bih_b, const float* __restrict__ bhh_b,
                        float* __restrict__ xg) {
    __shared__ __align__(16) float as[8][128];
    __shared__ __align__(16) float bs[8][128];
    int m0 = blockIdx.x * 128;     // 64 tiles
    int n0 = blockIdx.y * 128;     // 16 tiles
    int tid = threadIdx.x;
    int tx = tid & 15, ty = tid >> 4;
    int lr = tid >> 1;             // 0..127 tile row
    int lh = (tid & 1) * 4;        // k offset 0 or 4

    const float* arow = x + (size_t)(m0 + lr) * EMBD;
    const float* brow;
    {
        int n = n0 + lr;
        const float* w = (n < G4H) ? wih_f : wih_b;
        brow = w + (size_t)(n & 1023) * EMBD;
    }

    float acc[8][8];
    #pragma unroll
    for (int i = 0; i < 8; i++)
        #pragma unroll
        for (int j = 0; j < 8; j++) acc[i][j] = 0.f;

    for (int k0 = 0; k0 < EMBD; k0 += 8) {
        float4 av = *(const float4*)(arow + k0 + lh);
        float4 bv = *(const float4*)(brow + k0 + lh);
        __syncthreads();
        as[lh + 0][lr] = av.x; as[lh + 1][lr] = av.y; as[lh + 2][lr] = av.z; as[lh + 3][lr] = av.w;
        bs[lh + 0][lr] = bv.x; bs[lh + 1][lr] = bv.y; bs[lh + 2][lr] = bv.z; bs[lh + 3][lr] = bv.w;
        __syncthreads();
        #pragma unroll
        for (int kk = 0; kk < 8; kk++) {
            float4 a0 = *(const float4*)&as[kk][ty * 8];
            float4 a1 = *(const float4*)&as[kk][ty * 8 + 4];
            float4 b0 = *(const float4*)&bs[kk][tx * 8];
            float4 b1 = *(const float4*)&bs[kk][tx * 8 + 4];
            float a[8] = {a0.x, a0.y, a0.z, a0.w, a1.x, a1.y, a1.z, a1.w};
            float b[8] = {b0.x, b0.y, b0.z, b0.w, b1.x, b1.y, b1.z, b1.w};
            #pragma unroll
            for (int i = 0; i < 8; i++)
                #pragma unroll
                for (int j = 0; j < 8; j++) acc[i][j] += a[i] * b[j];
        }
    }

    int n = n0 + tx * 8;                 // tile stays within one dir (1024 % 128 == 0)
    int dir = n >> 10, g0 = n & 1023;
    const float* bih = dir ? bih_b : bih_f;
    const float* bhh = dir ? bhh_b : bhh_f;
    float bi[8], bh[8];
    #pragma unroll
    for (int j = 0; j < 8; j++) { bi[j] = bih[g0 + j]; bh[j] = bhh[g0 + j]; }
    float* ob = xg + (size_t)dir * 8192 * G4H;
    #pragma unroll
    for (int i = 0; i < 8; i++) {
        int m = m0 + ty * 8 + i;
        float v[8];
        #pragma unroll
        for (int j = 0; j < 8; j++) v[j] = (acc[i][j] + bi[j]) + bh[j];
        *(float4*)(ob + (size_t)m * G4H + g0)     = make_float4(v[0], v[1], v[2], v[3]);
        *(float4*)(ob + (size_t)m * G4H + g0 + 4) = make_float4(v[4], v[5], v[6], v[7]);
    }
}

// ---------------- Kernel 3b: zero sync state (every launch, after gemm) ----
__global__ void zero_sync(float* __restrict__ hx, int* __restrict__ flags) {
    int i = blockIdx.x * 256 + threadIdx.x;
    if (i < 64 * 512) hx[i] = 0.f;
    if (i < 128) flags[i] = 0;
}

// ---------------- Kernel 4: LSTM recurrence (2 WGs per chain) -------------
#define DOT4(W, K)                                              \
    a0 += (W).x * bcast(hv[((K) + 0) >> 6], ((K) + 0) & 63);    \
    a1 += (W).y * bcast(hv[((K) + 1) >> 6], ((K) + 1) & 63);    \
    a2 += (W).z * bcast(hv[((K) + 2) >> 6], ((K) + 2) & 63);    \
    a3 += (W).w * bcast(hv[((K) + 3) >> 6], ((K) + 3) & 63);

__launch_bounds__(512)
__global__ void lstm_rec(const float* __restrict__ xg,
                         const float* __restrict__ whh_f, const float* __restrict__ whh_b,
                         const float4* __restrict__ wpack,
                         float* __restrict__ h_all,
                         float* __restrict__ hx, int* __restrict__ flags) {
    int blk = blockIdx.x;            // 128
    int half = blk & 1;
    int chain = blk >> 1;            // 64
    int dir = chain & 1, b = chain >> 1;
    int g = threadIdx.x;             // 0..511
    int lane = g & 63;
    int unit0 = half * 128;
    int R = (g >> 7) * 256 + unit0 + (g & 127);    // global gate row

    const float* whh = dir ? whh_b : whh_f;
    const float4* wp = wpack + (size_t)(dir * 2 + half) * KSTR_G * 512 + g;
    const float* xgb = xg + (size_t)dir * 8192 * G4H + (size_t)b * SEQ * G4H + R;
    float* hxc = hx + chain * 512;                 // [2 parity][256 units]
    int* own_flag = flags + chain * 2 + half;
    int* par_flag = flags + chain * 2 + (1 - half);

    __shared__ __align__(16) float4 wlds[KLDS_G * 512];   // 147,456 B
    __shared__ float gates[512];                          //   2,048 B

    // one-time stages
    #pragma unroll
    for (int j = 0; j < KLDS_G; j++)
        wlds[j * 512 + g] = *(const float4*)(whh + (size_t)R * HDIM + KRES + j * 4);
    float4 wr[KRES / 4];
    #pragma unroll
    for (int i = 0; i < KRES / 4; i++)
        wr[i] = *(const float4*)(whh + (size_t)R * HDIM + i * 4);

    float c = 0.f;
    __syncthreads();

    for (int t = 0; t < SEQ; t++) {
        int s = dir ? (SEQ - 1 - t) : t;

        // issue h-independent long-latency loads before the wait
        float xval = xgb[(size_t)s * G4H];
        float4 sb[4];
        #pragma unroll
        for (int p = 0; p < 4; p++) sb[p] = wp[(size_t)p * 512];

        // wait for partner's h_{t-1}
        if (t > 0) {
            if (g == 0)
                while (__hip_atomic_load(par_flag, __ATOMIC_ACQUIRE,
                                         __HIP_MEMORY_SCOPE_AGENT) < t) {}
            __syncthreads();
        }

        // h_{t-1} lives at parity (t-1)&1 == (t+1)&1 ; zeroed for t=0
        int rp = (t + 1) & 1;
        float hv[4];
        #pragma unroll
        for (int j = 0; j < 4; j++)
            hv[j] = __hip_atomic_load(hxc + rp * 256 + j * 64 + lane,
                                      __ATOMIC_RELAXED, __HIP_MEMORY_SCOPE_AGENT);

        float a0 = xval, a1 = 0.f, a2 = 0.f, a3 = 0.f;

        // VGPR tier k = 0..15
        #pragma unroll
        for (int i = 0; i < KRES / 4; i++) {
            float4 w = wr[i];
            DOT4(w, i * 4)
        }
        // LDS tier k = 16..87
        #pragma unroll
        for (int j = 0; j < KLDS_G; j++) {
            float4 w = wlds[j * 512 + g];
            DOT4(w, KRES + j * 4)
        }
        // streamed tier k = 88..255, depth-4 ring
        #pragma unroll
        for (int j = 0; j < KSTR_G; j++) {
            float4 w = sb[j & 3];
            if (j + 4 < KSTR_G) sb[j & 3] = wp[(size_t)(j + 4) * 512];
            DOT4(w, KRES + 4 * KLDS_G + j * 4)
        }

        gates[g] = (a0 + a1) + (a2 + a3);
        __syncthreads();
        if (g < 128) {
            float gi = gates[g], gf = gates[128 + g], gg = gates[256 + g], go = gates[384 + g];
            float si = 1.f / (1.f + expf(-gi));
            float sf = 1.f / (1.f + expf(-gf));
            float so = 1.f / (1.f + expf(-go));
            c = sf * c + si * tanhf(gg);
            float h = so * tanhf(c);
            int u = unit0 + g;
            h_all[((size_t)b * SEQ + s) * 512 + dir * HDIM + u] = h;
            __hip_atomic_store(hxc + (t & 1) * 256 + u, h,
                               __ATOMIC_RELAXED, __HIP_MEMORY_SCOPE_AGENT);
        }
        __syncthreads();   // drains vmcnt: hx writes complete before flag
        if (g == 0)
            __hip_atomic_store(own_flag, t + 1,
                               __ATOMIC_RELEASE, __HIP_MEMORY_SCOPE_AGENT);
    }
}

// ---------------- Kernel 5: output projection (feats) ----------------
__global__ void feats_kernel(const float* __restrict__ h_all, const float* __restrict__ w_out,
                             const float* __restrict__ b_out, float* __restrict__ feats) {
    int p = blockIdx.x;            // 8192
    int lane = threadIdx.x;        // 64
    const float* h = h_all + (size_t)p * 512;
    for (int f = 0; f < TAGS; f++) {
        float s = 0.f;
        const float* w = w_out + f * 512;
        #pragma unroll
        for (int k = 0; k < 512; k += 64) s += h[k + lane] * w[k + lane];
        #pragma unroll
        for (int off = 32; off; off >>= 1) s += __shfl_down(s, off);
        if (lane == 0) feats[(size_t)p * TAGS + f] = s + b_out[f];
    }
}

// ---------------- Kernel 6: Viterbi decode ----------------
__global__ void viterbi_kernel(const float* __restrict__ feats, const float* __restrict__ trans,
                               float* __restrict__ out) {
    int b = blockIdx.x;            // 32
    int t = threadIdx.x;           // 64
    __shared__ float fv[TAGS], fvn[TAGS], tr[TAGS * TAGS];
    __shared__ int bp[SEQ][TAGS];  // 12 KB

    for (int i = t; i < TAGS * TAGS; i += 64) tr[i] = trans[i];
    if (t < TAGS) fv[t] = (t == START_IDX) ? 0.f : NEGV;
    __syncthreads();

    const float* fb = feats + (size_t)b * SEQ * TAGS;
    for (int s = 0; s < SEQ; s++) {
        if (t < TAGS) {
            float best = fv[0] + tr[t * TAGS + 0];
            int bi = 0;
            #pragma unroll
            for (int prev = 1; prev < TAGS; prev++) {
                float v = fv[prev] + tr[t * TAGS + prev];
                if (v > best) { best = v; bi = prev; }   // first-index argmax
            }
            bp[s][t] = bi;
            fvn[t] = best + fb[s * TAGS + t];
        }
        __syncthreads();
        if (t < TAGS) fv[t] = fvn[t];
        __syncthreads();
    }

    if (t == 0) {
        float best = fv[0] + tr[STOP_IDX * TAGS + 0];
        int bi = 0;
        #pragma unroll
        for (int p = 1; p < TAGS; p++) {
            float v = fv[p] + tr[STOP_IDX * TAGS + p];
            if (v > best) { best = v; bi = p; }
        }
        out[b] = best;                                   // score
        float* path = out + BATCH + (size_t)b * SEQ;
        int tag = bi;
        path[SEQ - 1] = (float)tag;
        for (int s = SEQ - 1; s >= 1; s--) {
            tag = bp[s][tag];
            path[s - 1] = (float)tag;
        }
    }
}

// ---------------- Launch ----------------
extern "C" void kernel_launch(void* const* d_in, const int* in_sizes, int n_in,
                              void* d_out, int out_size, void* d_ws, size_t ws_size,
                              hipStream_t stream) {
    const int*   sent  = (const int*)d_in[0];
    const float* emb   = (const float*)d_in[1];
    const float* wih_f = (const float*)d_in[2];
    const float* whh_f = (const float*)d_in[3];
    const float* bih_f = (const float*)d_in[4];
    const float* bhh_f = (const float*)d_in[5];
    const float* wih_b = (const float*)d_in[6];
    const float* whh_b = (const float*)d_in[7];
    const float* bih_b = (const float*)d_in[8];
    const float* bhh_b = (const float*)d_in[9];
    const float* w_out = (const float*)d_in[10];
    const float* b_out = (const float*)d_in[11];
    const float* trans = (const float*)d_in[12];
    float* ws    = (float*)d_ws;
    float* xg    = ws + WS_XG;
    float* x     = ws + WS_X;
    float* wpack = ws + WS_WPACK;
    float* h_all = ws + WS_HALL;
    float* feats = ws + WS_FEATS;
    // sync state lives in the x region (dead after gemm_xg; zeroed after it)
    float* hx    = ws + WS_X;
    int*   flags = (int*)(ws + WS_X + 64 * 512);
    float* out   = (float*)d_out;

    gather_x<<<BATCH * SEQ, 64, 0, stream>>>(sent, emb, x);
    pack_whh<<<(2 * 2 * KSTR_G * 512 + 255) / 256, 256, 0, stream>>>(whh_f, whh_b, (float4*)wpack);
    gemm_xg<<<dim3(64, 16), 256, 0, stream>>>(x, wih_f, wih_b, bih_f, bhh_f, bih_b, bhh_b, xg);
    zero_sync<<<128, 256, 0, stream>>>(hx, flags);
    lstm_rec<<<128, 512, 0, stream>>>(xg, whh_f, whh_b, (const float4*)wpack, h_all, hx, flags);
    feats_kernel<<<BATCH * SEQ, 64, 0, stream>>>(h_all, w_out, b_out, feats);
    viterbi_kernel<<<BATCH, 64, 0, stream>>>(feats, trans, out);
}